// Round 1
// baseline (456.961 us; speedup 1.0000x reference)
//
#include <hip/hip_runtime.h>

// ---------------- problem constants (fixed shapes per reference) ----------------
constexpr int LDIM = 4;     // lamb_len
constexpr int MDIM = 64;    // memory dim
constexpr int FDIM = 128;   // node feature dim
constexpr int EDIM = 128;   // embedding dim
constexpr int RAWD = 641;   // raw message dim
constexpr int HDIM = 320;   // MLP hidden
constexpr int LM   = LDIM * MDIM;   // 256
constexpr int KXY  = LM + FDIM;     // 384  (K of the [X|Y] GEMM)
constexpr int NXY  = 2 * HDIM;      // 640  (X cols | Y cols)

// ---------------- small event/node kernels ----------------
__global__ void k_init(int* t_node_bits, int* counts, int* cursor2, int* cursor, int Nn)
{
    int n = blockIdx.x * blockDim.x + threadIdx.x;
    if (n < Nn) {
        t_node_bits[n] = 0xBF800000;  // -1.0f; timestamps >= 0 so signed-int max works
        counts[n]  = 0;
        cursor2[n] = 0;
    }
    if (n == 0) cursor[0] = 0;
}

__global__ void k_ev1(const int* __restrict__ src, const float* __restrict__ ts,
                      int* t_node_bits, int* counts, int Bev)
{
    int b = blockIdx.x * blockDim.x + threadIdx.x;
    if (b >= Bev) return;
    int s = src[b];
    atomicMax(&t_node_bits[s], __float_as_int(ts[b]));
    atomicAdd(&counts[s], 1);
}

__global__ void k_node(const int* __restrict__ t_node_bits, const int* __restrict__ counts,
                       const float* __restrict__ last_update, const float* __restrict__ lambs,
                       float* t_safe, float* decay, int* start, int* cursor, int Nn)
{
    int n = blockIdx.x * blockDim.x + threadIdx.x;
    if (n >= Nn) return;
    int c = counts[n];
    float lu = last_update[n];
    float tsn = (c > 0) ? __int_as_float(t_node_bits[n]) : lu;
    t_safe[n] = tsn;
    float d = tsn - lu;
    #pragma unroll
    for (int li = 0; li < LDIM; ++li)
        decay[n * LDIM + li] = expf(-d * lambs[li]);
    start[n] = atomicAdd(cursor, c);   // arbitrary segment order is fine
}

__global__ void k_ev2(const int* __restrict__ src, const int* __restrict__ tgt,
                      const float* __restrict__ ts, const float* __restrict__ t_safe,
                      const int* __restrict__ start, int* cursor2,
                      int* sorted_tgt, float* sorted_dt, int Bev)
{
    int b = blockIdx.x * blockDim.x + threadIdx.x;
    if (b >= Bev) return;
    int s = src[b];
    int pos = start[s] + atomicAdd(&cursor2[s], 1);
    sorted_tgt[pos] = tgt[b];
    sorted_dt[pos]  = t_safe[s] - ts[b];
}

// ---------------- weight prep: Wpack[KXY][NXY], W2T, WeT, WsT ----------------
__global__ void k_prep(const float* __restrict__ W1, const float* __restrict__ W2,
                       const float* __restrict__ We, const float* __restrict__ Ws,
                       float* Wpack, float* W2T, float* WeT, float* WsT)
{
    int idx = blockIdx.x * blockDim.x + threadIdx.x;
    constexpr int T1 = KXY * NXY;    // 245760
    constexpr int T2 = HDIM * MDIM;  // 20480
    constexpr int T3 = LM * MDIM;    // 16384
    constexpr int T4 = MDIM * EDIM;  // 8192
    if (idx < T1) {
        int k = idx / NXY, j = idx % NXY;
        float v;
        if (j < HDIM) {
            v = (k < LM) ? W1[(long)j * RAWD + k] : 0.f;              // X cols: src-mem block
        } else {
            int h = j - HDIM;
            v = (k < LM) ? W1[(long)h * RAWD + LM + k]                 // Y cols: tgt-mem block
                         : W1[(long)h * RAWD + 2 * LM + (k - LM)];     //         tgt-feature block
        }
        Wpack[idx] = v;
    } else if (idx < T1 + T2) {
        int r = idx - T1; int k = r / MDIM, j = r % MDIM;
        W2T[r] = W2[(long)j * HDIM + k];
    } else if (idx < T1 + T2 + T3) {
        int r = idx - T1 - T2; int k = r / MDIM, j = r % MDIM;
        WeT[r] = We[(long)j * LM + k];
    } else if (idx < T1 + T2 + T3 + T4) {
        int r = idx - T1 - T2 - T3; int k = r / EDIM, j = r % EDIM;
        WsT[r] = Ws[(long)j * MDIM + k];
    }
}

// ---------------- gather: Z + X*S + b1 -> relu -> h[N*4][320] ----------------
__global__ __launch_bounds__(HDIM) void k_gather(
    const float* __restrict__ C1, const float* __restrict__ sorted_dt,
    const int* __restrict__ sorted_tgt, const int* __restrict__ start,
    const int* __restrict__ counts, const float* __restrict__ lambs,
    const float* __restrict__ W1, const float* __restrict__ b1,
    float* __restrict__ h, int Nn)
{
    const int tid = threadIdx.x;                 // 0..319 == hidden index
    const float l0 = lambs[0], l1 = lambs[1], l2 = lambs[2], l3 = lambs[3];
    const float bb = b1[tid];
    const float w1last = W1[(long)tid * RAWD + (RAWD - 1)];  // ones-column weight
    for (int n = blockIdx.x; n < Nn; n += gridDim.x) {
        int cnt = counts[n];
        if (cnt == 0) continue;                  // h row left as-is; masked in msg epilogue
        int st = start[n];
        float z0 = 0, z1 = 0, z2 = 0, z3 = 0;
        float s0 = 0, s1 = 0, s2 = 0, s3 = 0;
        for (int e = 0; e < cnt; ++e) {
            float dt = sorted_dt[st + e];
            int   t  = sorted_tgt[st + e];
            float w0 = expf(-dt * l0), w1 = expf(-dt * l1);
            float w2 = expf(-dt * l2), w3 = expf(-dt * l3);
            float yv = C1[(long)t * NXY + HDIM + tid];       // Y[t, tid], coalesced
            z0 += w0 * yv; z1 += w1 * yv; z2 += w2 * yv; z3 += w3 * yv;
            s0 += w0;      s1 += w1;      s2 += w2;      s3 += w3;
        }
        float xv = C1[(long)n * NXY + tid] + w1last;         // X[n, tid] + W1[:,640]
        long base = ((long)n * LDIM) * HDIM + tid;
        float h0 = xv * s0 + z0 + bb; h[base           ] = fmaxf(h0, 0.f);
        float h1 = xv * s1 + z1 + bb; h[base +     HDIM] = fmaxf(h1, 0.f);
        float h2 = xv * s2 + z2 + bb; h[base + 2 * HDIM] = fmaxf(h2, 0.f);
        float h3 = xv * s3 + z3 + bb; h[base + 3 * HDIM] = fmaxf(h3, 0.f);
    }
}

// ---------------- tiled f32 GEMM with fused epilogues ----------------
// C[M][N] = A[M][K] @ B[K][N];  A is a 2-pointer composite split at `ksplit`.
// EPI: 0 = plain store, 1 = msg->updated, 2 = leaky->e, 3 = leaky->theta-blend out
template <int BM, int BN, int BK, int TM, int TN, int EPI>
__global__ __launch_bounds__(256) void k_gemm(
    const float* __restrict__ A0, const float* __restrict__ A1,
    int lda0, int lda1, int ksplit,
    const float* __restrict__ Bmat, const float* __restrict__ bias,
    float* __restrict__ C, int M, int N, int K,
    const float* __restrict__ x1, const float* __restrict__ x2,
    const int* __restrict__ cnts, const float* __restrict__ theta)
{
    static_assert(TM % 4 == 0 && TN % 4 == 0, "");
    constexpr int RG = TM / 4, CG = TN / 4;
    constexpr int LDAS = BM + 4;                 // pad: 2-way (free) LDS banking
    __shared__ float As[BK][LDAS];
    __shared__ float Bs[BK][BN];
    constexpr int TX = BN / TN;                  // 16
    static_assert((BM / TM) * TX == 256, "");
    const int tid = threadIdx.x;
    const int tx = tid % TX;
    const int ty = tid / TX;
    const long m0 = (long)blockIdx.x * BM;
    const int  n0 = blockIdx.y * BN;

    float acc[TM][TN];
    #pragma unroll
    for (int i = 0; i < TM; ++i)
        #pragma unroll
        for (int j = 0; j < TN; ++j) acc[i][j] = 0.f;

    for (int k0 = 0; k0 < K; k0 += BK) {
        constexpr int NF4A = BM * BK / 4;        // float4 count, multiple of 256
        static_assert(NF4A % 256 == 0, "");
        #pragma unroll
        for (int f0 = 0; f0 < NF4A; f0 += 256) {
            int f = f0 + tid;
            int mm = f / (BK / 4);
            int kg = f % (BK / 4);
            long gm = m0 + mm;
            int  gk = k0 + kg * 4;
            float4 v = make_float4(0.f, 0.f, 0.f, 0.f);
            if (gm < M) {
                if (gk < ksplit) v = *(const float4*)(A0 + gm * (long)lda0 + gk);
                else             v = *(const float4*)(A1 + gm * (long)lda1 + (gk - ksplit));
            }
            As[kg * 4 + 0][mm] = v.x;
            As[kg * 4 + 1][mm] = v.y;
            As[kg * 4 + 2][mm] = v.z;
            As[kg * 4 + 3][mm] = v.w;
        }
        constexpr int NF4B = BK * BN / 4;
        static_assert(NF4B % 256 == 0, "");
        #pragma unroll
        for (int f0 = 0; f0 < NF4B; f0 += 256) {
            int f = f0 + tid;
            int kk = f / (BN / 4);
            int ng = f % (BN / 4);
            *(float4*)(&Bs[kk][ng * 4]) =
                *(const float4*)(Bmat + (long)(k0 + kk) * N + n0 + ng * 4);
        }
        __syncthreads();
        #pragma unroll
        for (int kk = 0; kk < BK; ++kk) {
            float af[TM], bf[TN];
            #pragma unroll
            for (int g = 0; g < RG; ++g) {
                float4 a4 = *(const float4*)(&As[kk][g * (BM / RG) + ty * 4]);
                af[g*4+0]=a4.x; af[g*4+1]=a4.y; af[g*4+2]=a4.z; af[g*4+3]=a4.w;
            }
            #pragma unroll
            for (int g = 0; g < CG; ++g) {
                float4 b4 = *(const float4*)(&Bs[kk][g * (BN / CG) + tx * 4]);
                bf[g*4+0]=b4.x; bf[g*4+1]=b4.y; bf[g*4+2]=b4.z; bf[g*4+3]=b4.w;
            }
            #pragma unroll
            for (int i = 0; i < TM; ++i)
                #pragma unroll
                for (int j = 0; j < TN; ++j)
                    acc[i][j] += af[i] * bf[j];
        }
        __syncthreads();
    }

    #pragma unroll
    for (int i = 0; i < TM; ++i) {
        long gm = m0 + (i / 4) * (BM / RG) + ty * 4 + (i % 4);
        if (gm >= M) continue;
        #pragma unroll
        for (int g = 0; g < CG; ++g) {
            int gn = n0 + g * (BN / CG) + tx * 4;
            long idx = gm * N + gn;
            float rr[4];
            #pragma unroll
            for (int c = 0; c < 4; ++c) {
                float va = acc[i][g * 4 + c];
                if constexpr (EPI == 0) {
                    rr[c] = va;
                } else if constexpr (EPI == 1) {
                    // msg -> updated: memory*decay + where(has, msg, 0)
                    float v = va + bias[gn + c];
                    bool has = cnts[gm >> 2] > 0;
                    rr[c] = x1[idx + c] * x2[gm] + (has ? v : 0.f);
                } else if constexpr (EPI == 2) {
                    float v = va + bias[gn + c];
                    rr[c] = v > 0.f ? v : 0.01f * v;
                } else {
                    float v = va + bias[gn + c];
                    v = v > 0.f ? v : 0.01f * v;
                    float th = theta[0];
                    rr[c] = th * x1[idx + c] + (1.f - th) * v;
                }
            }
            *(float4*)(C + idx) = make_float4(rr[0], rr[1], rr[2], rr[3]);
        }
    }
}

// ---------------- launcher ----------------
extern "C" void kernel_launch(void* const* d_in, const int* in_sizes, int n_in,
                              void* d_out, int out_size, void* d_ws, size_t ws_size,
                              hipStream_t stream)
{
    (void)n_in; (void)out_size; (void)ws_size;
    const float* node_features = (const float*)d_in[0];
    const float* memory        = (const float*)d_in[1];
    const float* last_update   = (const float*)d_in[2];
    const float* lambs         = (const float*)d_in[3];
    const float* theta         = (const float*)d_in[4];
    const float* static_emb    = (const float*)d_in[5];
    const float* W1            = (const float*)d_in[6];
    const float* b1            = (const float*)d_in[7];
    const float* W2            = (const float*)d_in[8];
    const float* b2            = (const float*)d_in[9];
    const float* We            = (const float*)d_in[10];
    const float* be            = (const float*)d_in[11];
    const float* Ws            = (const float*)d_in[12];
    const float* bs            = (const float*)d_in[13];
    const float* timestamps    = (const float*)d_in[14];
    const int*   src           = (const int*)d_in[15];
    const int*   tgt           = (const int*)d_in[16];
    float* out = (float*)d_out;

    const int Nn  = in_sizes[2];   // 20000
    const int Bev = in_sizes[14];  // 100000

    // workspace carve-out (≈182 MB total)
    char* base = (char*)d_ws;
    size_t off = 0;
    auto take = [&](size_t bytes) -> void* {
        off = (off + 255) & ~(size_t)255;
        void* r = base + off;
        off += bytes;
        return r;
    };
    int*   t_node_bits = (int*)  take((size_t)Nn * 4);
    int*   counts      = (int*)  take((size_t)Nn * 4);
    int*   startb      = (int*)  take((size_t)Nn * 4);
    int*   cursor2     = (int*)  take((size_t)Nn * 4);
    int*   cursor      = (int*)  take(256);
    float* t_safe      = (float*)take((size_t)Nn * 4);
    float* decay       = (float*)take((size_t)Nn * LDIM * 4);
    int*   sorted_tgt  = (int*)  take((size_t)Bev * 4);
    float* sorted_dt   = (float*)take((size_t)Bev * 4);
    float* Wpack       = (float*)take((size_t)KXY * NXY * 4);
    float* W2T         = (float*)take((size_t)HDIM * MDIM * 4);
    float* WeT         = (float*)take((size_t)LM * MDIM * 4);
    float* WsT         = (float*)take((size_t)MDIM * EDIM * 4);
    float* C1          = (float*)take((size_t)Nn * NXY * 4);          // [X|Y] 51.2 MB
    float* hbuf        = (float*)take((size_t)Nn * LDIM * HDIM * 4);  // 102.4 MB
    float* updated     = (float*)take((size_t)Nn * LM * 4);           // 20.5 MB
    float* ebuf        = (float*)take((size_t)Nn * MDIM * 4);         // 5.1 MB

    const int tb = 256;
    k_init<<<(Nn + tb - 1) / tb, tb, 0, stream>>>(t_node_bits, counts, cursor2, cursor, Nn);
    k_ev1<<<(Bev + tb - 1) / tb, tb, 0, stream>>>(src, timestamps, t_node_bits, counts, Bev);
    k_node<<<(Nn + tb - 1) / tb, tb, 0, stream>>>(t_node_bits, counts, last_update, lambs,
                                                  t_safe, decay, startb, cursor, Nn);
    k_ev2<<<(Bev + tb - 1) / tb, tb, 0, stream>>>(src, tgt, timestamps, t_safe,
                                                  startb, cursor2, sorted_tgt, sorted_dt, Bev);
    const int preptot = KXY * NXY + HDIM * MDIM + LM * MDIM + MDIM * EDIM;
    k_prep<<<(preptot + tb - 1) / tb, tb, 0, stream>>>(W1, W2, We, Ws, Wpack, W2T, WeT, WsT);

    // G1: C1[Nn][640] = [mem | nf] @ Wpack    (M=20000, N=640, K=384)
    {
        dim3 grid((Nn + 127) / 128, NXY / 128);
        k_gemm<128, 128, 16, 8, 8, 0><<<grid, 256, 0, stream>>>(
            memory, node_features, LM, FDIM, LM,
            Wpack, nullptr, C1, Nn, NXY, KXY,
            nullptr, nullptr, nullptr, nullptr);
    }

    // gather: h[Nn*4][320]
    k_gather<<<2048, HDIM, 0, stream>>>(C1, sorted_dt, sorted_tgt, startb, counts,
                                        lambs, W1, b1, hbuf, Nn);

    // G2: updated[Nn][256] = (h @ W2T + b2) masked + memory*decay   (M=80000, N=64, K=320)
    {
        dim3 grid((Nn * LDIM + 127) / 128, 1);
        k_gemm<128, 64, 16, 8, 4, 1><<<grid, 256, 0, stream>>>(
            hbuf, hbuf, HDIM, HDIM, HDIM,
            W2T, b2, updated, Nn * LDIM, MDIM, HDIM,
            memory, decay, counts, nullptr);
    }

    // G3a: e[Nn][64] = leaky(updated @ WeT + be)   (M=20000, N=64, K=256)
    {
        dim3 grid((Nn + 127) / 128, 1);
        k_gemm<128, 64, 16, 8, 4, 2><<<grid, 256, 0, stream>>>(
            updated, updated, LM, LM, LM,
            WeT, be, ebuf, Nn, MDIM, LM,
            nullptr, nullptr, nullptr, nullptr);
    }

    // G3b: out[Nn][128] = theta*static + (1-theta)*leaky(e @ WsT + bs)  (M=20000, N=128, K=64)
    {
        dim3 grid((Nn + 127) / 128, EDIM / 128);
        k_gemm<128, 128, 16, 8, 8, 3><<<grid, 256, 0, stream>>>(
            ebuf, ebuf, MDIM, MDIM, MDIM,
            WsT, bs, out, Nn, EDIM, MDIM,
            static_emb, nullptr, nullptr, theta);
    }
}

// Round 3
// 321.417 us; speedup vs baseline: 1.4217x; 1.4217x over previous
//
#include <hip/hip_runtime.h>

// ---------------- problem constants ----------------
constexpr int LDIM = 4;
constexpr int MDIM = 64;
constexpr int FDIM = 128;
constexpr int EDIM = 128;
constexpr int RAWD = 641;
constexpr int HDIM = 320;
constexpr int LM   = LDIM * MDIM;   // 256
constexpr int KXY  = LM + FDIM;     // 384
constexpr int NXY  = 2 * HDIM;      // 640

typedef short bf16x8 __attribute__((ext_vector_type(8)));
typedef short bf16x4 __attribute__((ext_vector_type(4)));
typedef float f32x4  __attribute__((ext_vector_type(4)));

__device__ __forceinline__ void split_bf16(float x, unsigned short& h, unsigned short& l)
{
    unsigned xb = __float_as_uint(x);
    unsigned short hh = (unsigned short)(xb >> 16);        // truncate to bf16
    float hf = __uint_as_float(((unsigned)hh) << 16);
    float r  = x - hf;                                      // exact in f32
    h = hh;
    l = (unsigned short)(__float_as_uint(r) >> 16);
}

// ---------------- small event/node kernels ----------------
__global__ void k_init(int* t_node_bits, int* counts, int* cursor2, int* cursor, int Nn)
{
    int n = blockIdx.x * blockDim.x + threadIdx.x;
    if (n < Nn) {
        t_node_bits[n] = 0xBF800000;  // -1.0f; timestamps >= 0
        counts[n]  = 0;
        cursor2[n] = 0;
    }
    if (n == 0) cursor[0] = 0;
}

__global__ void k_ev1(const int* __restrict__ src, const float* __restrict__ ts,
                      int* t_node_bits, int* counts, int Bev)
{
    int b = blockIdx.x * blockDim.x + threadIdx.x;
    if (b >= Bev) return;
    int s = src[b];
    atomicMax(&t_node_bits[s], __float_as_int(ts[b]));
    atomicAdd(&counts[s], 1);
}

__global__ void k_node(const int* __restrict__ t_node_bits, const int* __restrict__ counts,
                       const float* __restrict__ last_update, const float* __restrict__ lambs,
                       float* t_safe, float* decay, int* start, int* cursor, int Nn)
{
    int n = blockIdx.x * blockDim.x + threadIdx.x;
    if (n >= Nn) return;
    int c = counts[n];
    float lu = last_update[n];
    float tsn = (c > 0) ? __int_as_float(t_node_bits[n]) : lu;
    t_safe[n] = tsn;
    float d = tsn - lu;
    #pragma unroll
    for (int li = 0; li < LDIM; ++li)
        decay[n * LDIM + li] = expf(-d * lambs[li]);
    start[n] = atomicAdd(cursor, c);
}

__global__ void k_ev2(const int* __restrict__ src, const int* __restrict__ tgt,
                      const float* __restrict__ ts, const float* __restrict__ t_safe,
                      const int* __restrict__ start, int* cursor2,
                      const float* __restrict__ lambs,
                      int* sorted_tgt, float4* sorted_w, int Bev)
{
    int b = blockIdx.x * blockDim.x + threadIdx.x;
    if (b >= Bev) return;
    int s = src[b];
    int pos = start[s] + atomicAdd(&cursor2[s], 1);
    sorted_tgt[pos] = tgt[b];
    float dt = t_safe[s] - ts[b];
    sorted_w[pos] = make_float4(expf(-dt * lambs[0]), expf(-dt * lambs[1]),
                                expf(-dt * lambs[2]), expf(-dt * lambs[3]));
}

// ---------------- weight prep: all B-operands as [N][K] bf16 hi/lo ----------------
__global__ void k_prep(const float* __restrict__ W1, const float* __restrict__ W2,
                       const float* __restrict__ We, const float* __restrict__ Ws,
                       unsigned short* WpTh, unsigned short* WpTl,
                       unsigned short* W2h,  unsigned short* W2l,
                       unsigned short* Weh,  unsigned short* Wel,
                       unsigned short* Wsh,  unsigned short* Wsl)
{
    int idx = blockIdx.x * blockDim.x + threadIdx.x;
    constexpr int T1 = NXY * KXY;    // 245760  WpackT [640][384]
    constexpr int T2 = MDIM * HDIM;  // 20480   W2 [64][320]
    constexpr int T3 = MDIM * LM;    // 16384   We [64][256]
    constexpr int T4 = EDIM * MDIM;  // 8192    Ws [128][64]
    unsigned short h, l;
    if (idx < T1) {
        int n = idx / KXY, k = idx % KXY;
        float v;
        if (n < HDIM) {
            v = (k < LM) ? W1[(long)n * RAWD + k] : 0.f;           // X cols: src-mem block
        } else {
            int hh = n - HDIM;
            v = (k < LM) ? W1[(long)hh * RAWD + LM + k]             // Y cols: tgt-mem
                         : W1[(long)hh * RAWD + 2 * LM + (k - LM)]; //         tgt-feat
        }
        split_bf16(v, h, l); WpTh[idx] = h; WpTl[idx] = l;
    } else if (idx < T1 + T2) {
        int r = idx - T1;
        split_bf16(W2[r], h, l); W2h[r] = h; W2l[r] = l;            // already [n][k]
    } else if (idx < T1 + T2 + T3) {
        int r = idx - T1 - T2;
        split_bf16(We[r], h, l); Weh[r] = h; Wel[r] = l;
    } else if (idx < T1 + T2 + T3 + T4) {
        int r = idx - T1 - T2 - T3;
        split_bf16(Ws[r], h, l); Wsh[r] = h; Wsl[r] = l;
    }
}

// ---------------- gather: Z + X*S + b1 -> relu -> h hi/lo [N*4][320] ----------------
__global__ __launch_bounds__(HDIM) void k_gather(
    const float* __restrict__ C1, const float4* __restrict__ sorted_w,
    const int* __restrict__ sorted_tgt, const int* __restrict__ start,
    const int* __restrict__ counts,
    const float* __restrict__ W1, const float* __restrict__ b1,
    unsigned short* __restrict__ hh, unsigned short* __restrict__ hl, int Nn)
{
    const int tid = threadIdx.x;
    const float bb = b1[tid];
    const float w1last = W1[(long)tid * RAWD + (RAWD - 1)];
    for (int n = blockIdx.x; n < Nn; n += gridDim.x) {
        int cnt = counts[n];
        if (cnt == 0) continue;                  // poison rows masked in G2 epilogue
        int st = start[n];
        float z0 = 0, z1 = 0, z2 = 0, z3 = 0;
        float s0 = 0, s1 = 0, s2 = 0, s3 = 0;
        for (int e = 0; e < cnt; ++e) {
            float4 w = sorted_w[st + e];
            int    t = sorted_tgt[st + e];
            float yv = C1[(long)t * NXY + HDIM + tid];
            z0 += w.x * yv; z1 += w.y * yv; z2 += w.z * yv; z3 += w.w * yv;
            s0 += w.x;      s1 += w.y;      s2 += w.z;      s3 += w.w;
        }
        float xv = C1[(long)n * NXY + tid] + w1last;
        long base = ((long)n * LDIM) * HDIM + tid;
        unsigned short a, b_;
        float h0 = fmaxf(xv * s0 + z0 + bb, 0.f);
        split_bf16(h0, a, b_); hh[base] = a; hl[base] = b_;
        float h1 = fmaxf(xv * s1 + z1 + bb, 0.f);
        split_bf16(h1, a, b_); hh[base + HDIM] = a; hl[base + HDIM] = b_;
        float h2 = fmaxf(xv * s2 + z2 + bb, 0.f);
        split_bf16(h2, a, b_); hh[base + 2 * HDIM] = a; hl[base + 2 * HDIM] = b_;
        float h3 = fmaxf(xv * s3 + z3 + bb, 0.f);
        split_bf16(h3, a, b_); hh[base + 3 * HDIM] = a; hl[base + 3 * HDIM] = b_;
    }
}

// ---------------- split-bf16 MFMA GEMM template ----------------
// C[M][N] = A[M][K] @ B[K][N] via 3-product bf16 split MFMA (16x16x32).
// A: AF32=1 -> two f32 row-major sources split at ksplit (converted on the fly);
//    AF32=0 -> pre-split bf16 hi/lo, row-major [M][K].
// B: pre-split bf16 hi/lo, stored [N][K] row-major.
// LDS tiles [rows][32k] bf16, 16B-chunk XOR swizzle: phys_chunk = chunk ^ (row&3).
// EPI: 0 plain f32; 1 msg->updated(hi/lo); 2 leaky->e(hi/lo); 3 leaky->theta-blend f32.
template <int BN, int AF32, int EPI>
__global__ __launch_bounds__(256) void k_mgemm(
    const float* __restrict__ A0, const float* __restrict__ A1,
    int lda0, int lda1, int ksplit,
    const unsigned short* __restrict__ Agh, const unsigned short* __restrict__ Agl,
    const unsigned short* __restrict__ Bgh, const unsigned short* __restrict__ Bgl,
    float* __restrict__ Cf, unsigned short* __restrict__ Coh, unsigned short* __restrict__ Col,
    int M, int N, int K,
    const float* __restrict__ bias, const float* __restrict__ x1,
    const float* __restrict__ x2, const int* __restrict__ icnts,
    const float* __restrict__ theta)
{
    constexpr int BM = 128, BK = 32;
    constexpr int SN = BN / 32;                 // n-subtiles per wave (2x2 wave grid)
    __shared__ unsigned short Ash[BM * BK], Asl[BM * BK];
    __shared__ unsigned short Bsh[BN * BK], Bsl[BN * BK];
    const int tid  = threadIdx.x;
    const int w    = tid >> 6, lane = tid & 63;
    const int wm   = w >> 1,   wn   = w & 1;
    const int lrow = lane & 15, lq = lane >> 4;
    const long m0 = (long)blockIdx.x * BM;
    const int  n0 = blockIdx.y * BN;

    f32x4 acc[4][SN];
    #pragma unroll
    for (int s = 0; s < 4; ++s)
        #pragma unroll
        for (int t = 0; t < SN; ++t) acc[s][t] = (f32x4){0.f, 0.f, 0.f, 0.f};

    for (int k0 = 0; k0 < K; k0 += BK) {
        // ---- stage A ----
        if constexpr (AF32) {
            #pragma unroll
            for (int it = 0; it < 4; ++it) {
                int c = it * 256 + tid;          // float4-chunk id; 8 per row
                int row = c >> 3, kc = c & 7;
                long gm = m0 + row; if (gm > M - 1) gm = M - 1;
                int gk = k0 + kc * 4;
                const float* sp = (gk < ksplit) ? (A0 + gm * (long)lda0 + gk)
                                                : (A1 + gm * (long)lda1 + (gk - ksplit));
                float4 v = *(const float4*)sp;
                unsigned short h0,l0,h1,l1,h2,l2,h3,l3;
                split_bf16(v.x, h0, l0); split_bf16(v.y, h1, l1);
                split_bf16(v.z, h2, l2); split_bf16(v.w, h3, l3);
                int soff = row * BK + (((kc >> 1) ^ (row & 3)) << 3) + (kc & 1) * 4;
                *(bf16x4*)&Ash[soff] = (bf16x4){(short)h0,(short)h1,(short)h2,(short)h3};
                *(bf16x4*)&Asl[soff] = (bf16x4){(short)l0,(short)l1,(short)l2,(short)l3};
            }
        } else {
            #pragma unroll
            for (int it = 0; it < 2; ++it) {
                int c = it * 256 + tid;          // 16B-chunk id; 4 per row
                int row = c >> 2, kc = c & 3;
                long gm = m0 + row; if (gm > M - 1) gm = M - 1;
                long goff = gm * (long)K + k0 + kc * 8;
                int soff = row * BK + ((kc ^ (row & 3)) << 3);
                *(int4*)&Ash[soff] = *(const int4*)(Agh + goff);
                *(int4*)&Asl[soff] = *(const int4*)(Agl + goff);
            }
        }
        // ---- stage B ----
        #pragma unroll
        for (int it = 0; it < BN / 64; ++it) {
            int c = it * 256 + tid;
            int row = c >> 2, kc = c & 3;
            long goff = (long)(n0 + row) * K + k0 + kc * 8;
            int soff = row * BK + ((kc ^ (row & 3)) << 3);
            *(int4*)&Bsh[soff] = *(const int4*)(Bgh + goff);
            *(int4*)&Bsl[soff] = *(const int4*)(Bgl + goff);
        }
        __syncthreads();

        bf16x8 ah[4], al[4], bh[SN], bl[SN];
        #pragma unroll
        for (int s = 0; s < 4; ++s) {
            int row = wm * 64 + s * 16 + lrow;
            int off = row * BK + ((lq ^ (row & 3)) << 3);
            ah[s] = *(const bf16x8*)&Ash[off];
            al[s] = *(const bf16x8*)&Asl[off];
        }
        #pragma unroll
        for (int t = 0; t < SN; ++t) {
            int row = wn * (BN / 2) + t * 16 + lrow;
            int off = row * BK + ((lq ^ (row & 3)) << 3);
            bh[t] = *(const bf16x8*)&Bsh[off];
            bl[t] = *(const bf16x8*)&Bsl[off];
        }
        #pragma unroll
        for (int s = 0; s < 4; ++s)
            #pragma unroll
            for (int t = 0; t < SN; ++t) {
                acc[s][t] = __builtin_amdgcn_mfma_f32_16x16x32_bf16(ah[s], bh[t], acc[s][t], 0, 0, 0);
                acc[s][t] = __builtin_amdgcn_mfma_f32_16x16x32_bf16(ah[s], bl[t], acc[s][t], 0, 0, 0);
                acc[s][t] = __builtin_amdgcn_mfma_f32_16x16x32_bf16(al[s], bh[t], acc[s][t], 0, 0, 0);
            }
        __syncthreads();
    }

    // ---- epilogue ----
    float th = 0.f;
    if constexpr (EPI == 3) th = theta[0];
    #pragma unroll
    for (int s = 0; s < 4; ++s) {
        #pragma unroll
        for (int t = 0; t < SN; ++t) {
            #pragma unroll
            for (int r = 0; r < 4; ++r) {
                long grow = m0 + wm * 64 + s * 16 + lq * 4 + r;
                if (grow >= M) continue;
                int col = n0 + wn * (BN / 2) + t * 16 + lrow;
                float v = acc[s][t][r];
                long idx = grow * (long)N + col;
                if constexpr (EPI == 0) {
                    Cf[idx] = v;
                } else if constexpr (EPI == 1) {
                    float vb = v + bias[col];
                    bool has = icnts[grow >> 2] > 0;
                    float u = x1[idx] * x2[grow] + (has ? vb : 0.f);
                    unsigned short hq, lq2; split_bf16(u, hq, lq2);
                    Coh[idx] = hq; Col[idx] = lq2;
                } else if constexpr (EPI == 2) {
                    float u = v + bias[col];
                    u = u > 0.f ? u : 0.01f * u;
                    unsigned short hq, lq2; split_bf16(u, hq, lq2);
                    Coh[idx] = hq; Col[idx] = lq2;
                } else {
                    float u = v + bias[col];
                    u = u > 0.f ? u : 0.01f * u;
                    Cf[idx] = th * x1[idx] + (1.f - th) * u;
                }
            }
        }
    }
}

// ---------------- launcher ----------------
extern "C" void kernel_launch(void* const* d_in, const int* in_sizes, int n_in,
                              void* d_out, int out_size, void* d_ws, size_t ws_size,
                              hipStream_t stream)
{
    (void)n_in; (void)out_size; (void)ws_size;
    const float* node_features = (const float*)d_in[0];
    const float* memory        = (const float*)d_in[1];
    const float* last_update   = (const float*)d_in[2];
    const float* lambs         = (const float*)d_in[3];
    const float* theta         = (const float*)d_in[4];
    const float* static_emb    = (const float*)d_in[5];
    const float* W1            = (const float*)d_in[6];
    const float* b1            = (const float*)d_in[7];
    const float* W2            = (const float*)d_in[8];
    const float* b2            = (const float*)d_in[9];
    const float* We            = (const float*)d_in[10];
    const float* be            = (const float*)d_in[11];
    const float* Ws            = (const float*)d_in[12];
    const float* bs            = (const float*)d_in[13];
    const float* timestamps    = (const float*)d_in[14];
    const int*   src           = (const int*)d_in[15];
    const int*   tgt           = (const int*)d_in[16];
    float* out = (float*)d_out;

    const int Nn  = in_sizes[2];   // 20000
    const int Bev = in_sizes[14];  // 100000

    char* base = (char*)d_ws;
    size_t off = 0;
    auto take = [&](size_t bytes) -> void* {
        off = (off + 255) & ~(size_t)255;
        void* r = base + off;
        off += bytes;
        return r;
    };
    int*   t_node_bits = (int*)  take((size_t)Nn * 4);
    int*   counts      = (int*)  take((size_t)Nn * 4);
    int*   startb      = (int*)  take((size_t)Nn * 4);
    int*   cursor2     = (int*)  take((size_t)Nn * 4);
    int*   cursor      = (int*)  take(256);
    float* t_safe      = (float*)take((size_t)Nn * 4);
    float* decay       = (float*)take((size_t)Nn * LDIM * 4);
    int*   sorted_tgt  = (int*)  take((size_t)Bev * 4);
    float4* sorted_w   = (float4*)take((size_t)Bev * 16);
    unsigned short* WpTh = (unsigned short*)take((size_t)NXY * KXY * 2);
    unsigned short* WpTl = (unsigned short*)take((size_t)NXY * KXY * 2);
    unsigned short* W2h  = (unsigned short*)take((size_t)MDIM * HDIM * 2);
    unsigned short* W2l  = (unsigned short*)take((size_t)MDIM * HDIM * 2);
    unsigned short* Weh  = (unsigned short*)take((size_t)MDIM * LM * 2);
    unsigned short* Wel  = (unsigned short*)take((size_t)MDIM * LM * 2);
    unsigned short* Wsh  = (unsigned short*)take((size_t)EDIM * MDIM * 2);
    unsigned short* Wsl  = (unsigned short*)take((size_t)EDIM * MDIM * 2);
    float*          C1   = (float*)take((size_t)Nn * NXY * 4);                 // 51.2 MB
    unsigned short* hh   = (unsigned short*)take((size_t)Nn * LDIM * HDIM * 2);// 51.2 MB
    unsigned short* hl   = (unsigned short*)take((size_t)Nn * LDIM * HDIM * 2);// 51.2 MB
    unsigned short* updh = (unsigned short*)take((size_t)Nn * LM * 2);         // 10.2 MB
    unsigned short* updl = (unsigned short*)take((size_t)Nn * LM * 2);
    unsigned short* eh   = (unsigned short*)take((size_t)Nn * MDIM * 2);
    unsigned short* el   = (unsigned short*)take((size_t)Nn * MDIM * 2);

    const int tb = 256;
    k_init<<<(Nn + tb - 1) / tb, tb, 0, stream>>>(t_node_bits, counts, cursor2, cursor, Nn);
    k_ev1<<<(Bev + tb - 1) / tb, tb, 0, stream>>>(src, timestamps, t_node_bits, counts, Bev);
    k_node<<<(Nn + tb - 1) / tb, tb, 0, stream>>>(t_node_bits, counts, last_update, lambs,
                                                  t_safe, decay, startb, cursor, Nn);
    k_ev2<<<(Bev + tb - 1) / tb, tb, 0, stream>>>(src, tgt, timestamps, t_safe,
                                                  startb, cursor2, lambs,
                                                  sorted_tgt, sorted_w, Bev);
    const int preptot = NXY * KXY + MDIM * HDIM + MDIM * LM + EDIM * MDIM;
    k_prep<<<(preptot + tb - 1) / tb, tb, 0, stream>>>(W1, W2, We, Ws,
                                                       WpTh, WpTl, W2h, W2l,
                                                       Weh, Wel, Wsh, Wsl);

    const int mb1 = (Nn + 127) / 128;   // 157

    // G1: C1[20000][640] = [mem | nf] @ WpackT'   (K=384), f32 A converted on the fly
    k_mgemm<128, 1, 0><<<dim3(mb1, NXY / 128), 256, 0, stream>>>(
        memory, node_features, LM, FDIM, LM,
        nullptr, nullptr, WpTh, WpTl,
        C1, nullptr, nullptr, Nn, NXY, KXY,
        nullptr, nullptr, nullptr, nullptr, nullptr);

    // gather: h hi/lo [80000][320]
    k_gather<<<2048, HDIM, 0, stream>>>(C1, sorted_w, sorted_tgt, startb, counts,
                                        W1, b1, hh, hl, Nn);

    // G2: updated hi/lo = (h @ W2^T + b2) masked + memory*decay   (M=80000, N=64, K=320)
    k_mgemm<64, 0, 1><<<dim3(Nn * LDIM / 128, 1), 256, 0, stream>>>(
        nullptr, nullptr, 0, 0, 0,
        hh, hl, W2h, W2l,
        nullptr, updh, updl, Nn * LDIM, MDIM, HDIM,
        b2, memory, decay, counts, nullptr);

    // G3a: e hi/lo = leaky(updated @ We^T + be)   (M=20000, N=64, K=256)
    k_mgemm<64, 0, 2><<<dim3(mb1, 1), 256, 0, stream>>>(
        nullptr, nullptr, 0, 0, 0,
        updh, updl, Weh, Wel,
        nullptr, eh, el, Nn, MDIM, LM,
        be, nullptr, nullptr, nullptr, nullptr);

    // G3b: out = theta*static + (1-theta)*leaky(e @ Ws^T + bs)   (M=20000, N=128, K=64)
    k_mgemm<128, 0, 3><<<dim3(mb1, 1), 256, 0, stream>>>(
        nullptr, nullptr, 0, 0, 0,
        eh, el, Wsh, Wsl,
        out, nullptr, nullptr, Nn, EDIM, MDIM,
        bs, static_emb, nullptr, nullptr, theta);
}

// Round 5
// 299.371 us; speedup vs baseline: 1.5264x; 1.0736x over previous
//
#include <hip/hip_runtime.h>

// ---------------- problem constants ----------------
constexpr int LDIM = 4;
constexpr int MDIM = 64;
constexpr int FDIM = 128;
constexpr int EDIM = 128;
constexpr int RAWD = 641;
constexpr int HDIM = 320;
constexpr int LM   = LDIM * MDIM;   // 256
constexpr int KXY  = LM + FDIM;     // 384
constexpr int NXY  = 2 * HDIM;      // 640

typedef _Float16 f16x8 __attribute__((ext_vector_type(8)));
typedef float    f32x4 __attribute__((ext_vector_type(4)));

constexpr float WSCALE  = 256.f;       // weights pre-scaled so lo-plane is f16-normal
constexpr float WSINV   = 1.f / 256.f; // exact pow2, applied in epilogue

// ---------------- small event/node kernels ----------------
__global__ void k_init(int* t_node_bits, int* counts, int* cursor2, int* cursor, int Nn)
{
    int n = blockIdx.x * blockDim.x + threadIdx.x;
    if (n < Nn) {
        t_node_bits[n] = 0xBF800000;  // -1.0f; timestamps >= 0
        counts[n]  = 0;
        cursor2[n] = 0;
    }
    if (n == 0) cursor[0] = 0;
}

__global__ void k_ev1(const int* __restrict__ src, const float* __restrict__ ts,
                      int* t_node_bits, int* counts, int Bev)
{
    int b = blockIdx.x * blockDim.x + threadIdx.x;
    if (b >= Bev) return;
    int s = src[b];
    atomicMax(&t_node_bits[s], __float_as_int(ts[b]));
    atomicAdd(&counts[s], 1);
}

__global__ void k_node(const int* __restrict__ t_node_bits, const int* __restrict__ counts,
                       const float* __restrict__ last_update, const float* __restrict__ lambs,
                       float* t_safe, float* decay, int* start, int* cursor, int Nn)
{
    int n = blockIdx.x * blockDim.x + threadIdx.x;
    if (n >= Nn) return;
    int c = counts[n];
    float lu = last_update[n];
    float tsn = (c > 0) ? __int_as_float(t_node_bits[n]) : lu;
    t_safe[n] = tsn;
    float d = tsn - lu;
    #pragma unroll
    for (int li = 0; li < LDIM; ++li)
        decay[n * LDIM + li] = expf(-d * lambs[li]);
    start[n] = atomicAdd(cursor, c);
}

__global__ void k_ev2(const int* __restrict__ src, const int* __restrict__ tgt,
                      const float* __restrict__ ts, const float* __restrict__ t_safe,
                      const int* __restrict__ start, int* cursor2,
                      const float* __restrict__ lambs,
                      int* sorted_tgt, float4* sorted_w, int Bev)
{
    int b = blockIdx.x * blockDim.x + threadIdx.x;
    if (b >= Bev) return;
    int s = src[b];
    int pos = start[s] + atomicAdd(&cursor2[s], 1);
    sorted_tgt[pos] = tgt[b];
    float dt = t_safe[s] - ts[b];
    sorted_w[pos] = make_float4(expf(-dt * lambs[0]), expf(-dt * lambs[1]),
                                expf(-dt * lambs[2]), expf(-dt * lambs[3]));
}

// ---------------- pack [mem | nf] -> f16 A1 [Nn][384] ----------------
__global__ void k_half(const float* __restrict__ mem, const float* __restrict__ nf,
                       _Float16* __restrict__ A1, int total)
{
    int idx = blockIdx.x * blockDim.x + threadIdx.x;
    if (idx >= total) return;
    int n = idx / KXY, k = idx % KXY;
    float v = (k < LM) ? mem[(long)n * LM + k] : nf[(long)n * FDIM + (k - LM)];
    A1[idx] = (_Float16)v;
}

// ---------------- weight prep: B-operands [N][K], scaled f16 hi/lo ----------------
__global__ void k_prep(const float* __restrict__ W1, const float* __restrict__ W2,
                       const float* __restrict__ We, const float* __restrict__ Ws,
                       _Float16* WpH, _Float16* WpL, _Float16* W2H, _Float16* W2L,
                       _Float16* WeH, _Float16* WeL, _Float16* WsH, _Float16* WsL)
{
    int idx = blockIdx.x * blockDim.x + threadIdx.x;
    constexpr int T1 = NXY * KXY;    // 245760  Wpack [640][384]
    constexpr int T2 = MDIM * HDIM;  // 20480   W2 [64][320]
    constexpr int T3 = MDIM * LM;    // 16384   We [64][256]
    constexpr int T4 = EDIM * MDIM;  // 8192    Ws [128][64]
    float v; _Float16 *H, *L; int o;
    if (idx < T1) {
        int n = idx / KXY, k = idx % KXY;
        if (n < HDIM) {
            v = (k < LM) ? W1[(long)n * RAWD + k] : 0.f;            // X cols: src-mem
        } else {
            int hh = n - HDIM;
            v = (k < LM) ? W1[(long)hh * RAWD + LM + k]              // Y cols: tgt-mem
                         : W1[(long)hh * RAWD + 2 * LM + (k - LM)];  //         tgt-feat
        }
        H = WpH; L = WpL; o = idx;
    } else if (idx < T1 + T2) {
        o = idx - T1; v = W2[o]; H = W2H; L = W2L;                   // [64][320] = [n][k]
    } else if (idx < T1 + T2 + T3) {
        o = idx - T1 - T2; v = We[o]; H = WeH; L = WeL;              // [64][256]
    } else if (idx < T1 + T2 + T3 + T4) {
        o = idx - T1 - T2 - T3; v = Ws[o]; H = WsH; L = WsL;         // [128][64]
    } else return;
    float xs = WSCALE * v;
    _Float16 hh = (_Float16)xs;
    _Float16 ll = (_Float16)(xs - (float)hh);
    H[o] = hh; L[o] = ll;
}

// ---------------- gather: wave-per-node, f16 in/out ----------------
__global__ __launch_bounds__(256) void k_gather(
    const _Float16* __restrict__ C1, const float4* __restrict__ sorted_w,
    const int* __restrict__ sorted_tgt, const int* __restrict__ startb,
    const int* __restrict__ counts,
    const float* __restrict__ W1, const float* __restrict__ b1,
    _Float16* __restrict__ h, int Nn)
{
    const int lane = threadIdx.x & 63;
    const int wv   = threadIdx.x >> 6;          // wave id 0..3, one node per wave
    float bb[5], wl[5];
    #pragma unroll
    for (int c = 0; c < 5; ++c) {
        int hi = c * 64 + lane;
        bb[c] = b1[hi];
        wl[c] = W1[(long)hi * RAWD + (RAWD - 1)];   // ones-column weight
    }
    for (int n = blockIdx.x * 4 + wv; n < Nn; n += gridDim.x * 4) {
        int cnt = counts[n];
        if (cnt == 0) continue;                  // row poison masked in G2 epilogue
        int st = startb[n];
        float z[5][4];
        float sw[4] = {0.f, 0.f, 0.f, 0.f};
        #pragma unroll
        for (int c = 0; c < 5; ++c)
            #pragma unroll
            for (int li = 0; li < 4; ++li) z[c][li] = 0.f;
        for (int e = 0; e < cnt; ++e) {
            float4 w = sorted_w[st + e];
            int    t = sorted_tgt[st + e];
            const _Float16* yr = C1 + (long)t * NXY + HDIM;
            sw[0] += w.x; sw[1] += w.y; sw[2] += w.z; sw[3] += w.w;
            #pragma unroll
            for (int c = 0; c < 5; ++c) {
                float yv = (float)yr[c * 64 + lane];
                z[c][0] += w.x * yv; z[c][1] += w.y * yv;
                z[c][2] += w.z * yv; z[c][3] += w.w * yv;
            }
        }
        #pragma unroll
        for (int c = 0; c < 5; ++c) {
            float xv = (float)C1[(long)n * NXY + c * 64 + lane] + wl[c];
            #pragma unroll
            for (int li = 0; li < 4; ++li) {
                float hv = xv * sw[li] + z[c][li] + bb[c];
                h[((long)n * LDIM + li) * HDIM + c * 64 + lane] = (_Float16)fmaxf(hv, 0.f);
            }
        }
    }
}

// ---------------- f16 2-product MFMA GEMM ----------------
// C[M][N] = A[M][K](f16) @ (Bh+Bl)[K][N], B stored [N][K] scaled by 256.
// LDS [rows][32k] f16, 16B-chunk XOR swizzle: phys_chunk = chunk ^ (row&3).
// EPI: 0 -> f16 C1; 1 -> updated f16 (mem*decay + mask); 2 -> leaky f16; 3 -> f32 blend out.
template <int BN, int EPI>
__global__ __launch_bounds__(256) void k_mgemm(
    const _Float16* __restrict__ Ag,
    const _Float16* __restrict__ Bgh, const _Float16* __restrict__ Bgl,
    _Float16* __restrict__ Ch, float* __restrict__ Cf,
    int M, int N, int K,
    const float* __restrict__ bias, const float* __restrict__ x1,
    const float* __restrict__ x2, const int* __restrict__ icnts,
    const float* __restrict__ theta)
{
    constexpr int BM = 128, BK = 32;
    constexpr int SN = BN / 32;                 // n-subtiles per wave (2x2 wave grid)
    __shared__ _Float16 Ash[BM * BK];
    __shared__ _Float16 Bsh[BN * BK], Bsl[BN * BK];
    const int tid  = threadIdx.x;
    const int w    = tid >> 6, lane = tid & 63;
    const int wm   = w >> 1,   wn   = w & 1;
    const int lrow = lane & 15, lq = lane >> 4;
    const long m0 = (long)blockIdx.x * BM;
    const int  n0 = blockIdx.y * BN;

    f32x4 acc[4][SN];
    #pragma unroll
    for (int s = 0; s < 4; ++s)
        #pragma unroll
        for (int t = 0; t < SN; ++t) acc[s][t] = (f32x4){0.f, 0.f, 0.f, 0.f};

    for (int k0 = 0; k0 < K; k0 += BK) {
        // ---- stage A: 128 rows x 4 16B-chunks = 512 chunks ----
        #pragma unroll
        for (int it = 0; it < 2; ++it) {
            int c = it * 256 + tid;
            int row = c >> 2, kc = c & 3;
            long gm = m0 + row; if (gm > M - 1) gm = M - 1;
            long goff = gm * (long)K + k0 + kc * 8;
            int soff = row * BK + ((kc ^ (row & 3)) << 3);
            *(int4*)&Ash[soff] = *(const int4*)(Ag + goff);
        }
        // ---- stage B: BN rows x 4 chunks per plane ----
        #pragma unroll
        for (int it = 0; it < BN / 64; ++it) {
            int c = it * 256 + tid;
            int row = c >> 2, kc = c & 3;
            long goff = (long)(n0 + row) * K + k0 + kc * 8;
            int soff = row * BK + ((kc ^ (row & 3)) << 3);
            *(int4*)&Bsh[soff] = *(const int4*)(Bgh + goff);
            *(int4*)&Bsl[soff] = *(const int4*)(Bgl + goff);
        }
        __syncthreads();

        f16x8 a[4], bh[SN], bl[SN];
        #pragma unroll
        for (int s = 0; s < 4; ++s) {
            int row = wm * 64 + s * 16 + lrow;
            int off = row * BK + ((lq ^ (row & 3)) << 3);
            a[s] = *(const f16x8*)&Ash[off];
        }
        #pragma unroll
        for (int t = 0; t < SN; ++t) {
            int row = wn * (BN / 2) + t * 16 + lrow;
            int off = row * BK + ((lq ^ (row & 3)) << 3);
            bh[t] = *(const f16x8*)&Bsh[off];
            bl[t] = *(const f16x8*)&Bsl[off];
        }
        #pragma unroll
        for (int s = 0; s < 4; ++s)
            #pragma unroll
            for (int t = 0; t < SN; ++t) {
                acc[s][t] = __builtin_amdgcn_mfma_f32_16x16x32_f16(a[s], bh[t], acc[s][t], 0, 0, 0);
                acc[s][t] = __builtin_amdgcn_mfma_f32_16x16x32_f16(a[s], bl[t], acc[s][t], 0, 0, 0);
            }
        __syncthreads();
    }

    // ---- epilogue (undo the 256x weight scale here) ----
    float th = 0.f;
    if constexpr (EPI == 3) th = theta[0];
    #pragma unroll
    for (int s = 0; s < 4; ++s) {
        #pragma unroll
        for (int t = 0; t < SN; ++t) {
            #pragma unroll
            for (int r = 0; r < 4; ++r) {
                long grow = m0 + wm * 64 + s * 16 + lq * 4 + r;
                if (grow >= M) continue;
                int col = n0 + wn * (BN / 2) + t * 16 + lrow;
                float v = acc[s][t][r] * WSINV;
                long idx = grow * (long)N + col;
                if constexpr (EPI == 0) {
                    Ch[idx] = (_Float16)v;
                } else if constexpr (EPI == 1) {
                    float vb = v + bias[col];
                    bool has = icnts[grow >> 2] > 0;
                    float u = x1[idx] * x2[grow] + (has ? vb : 0.f);
                    Ch[idx] = (_Float16)u;
                } else if constexpr (EPI == 2) {
                    float u = v + bias[col];
                    u = u > 0.f ? u : 0.01f * u;
                    Ch[idx] = (_Float16)u;
                } else {
                    float u = v + bias[col];
                    u = u > 0.f ? u : 0.01f * u;
                    Cf[idx] = th * x1[idx] + (1.f - th) * u;
                }
            }
        }
    }
}

// ---------------- launcher ----------------
extern "C" void kernel_launch(void* const* d_in, const int* in_sizes, int n_in,
                              void* d_out, int out_size, void* d_ws, size_t ws_size,
                              hipStream_t stream)
{
    (void)n_in; (void)out_size; (void)ws_size;
    const float* node_features = (const float*)d_in[0];
    const float* memory        = (const float*)d_in[1];
    const float* last_update   = (const float*)d_in[2];
    const float* lambs         = (const float*)d_in[3];
    const float* theta         = (const float*)d_in[4];
    const float* static_emb    = (const float*)d_in[5];
    const float* W1            = (const float*)d_in[6];
    const float* b1            = (const float*)d_in[7];
    const float* W2            = (const float*)d_in[8];
    const float* b2            = (const float*)d_in[9];
    const float* We            = (const float*)d_in[10];
    const float* be            = (const float*)d_in[11];
    const float* Ws            = (const float*)d_in[12];
    const float* bs            = (const float*)d_in[13];
    const float* timestamps    = (const float*)d_in[14];
    const int*   src           = (const int*)d_in[15];
    const int*   tgt           = (const int*)d_in[16];
    float* out = (float*)d_out;

    const int Nn  = in_sizes[2];   // 20000
    const int Bev = in_sizes[14];  // 100000

    char* base = (char*)d_ws;
    size_t off = 0;
    auto take = [&](size_t bytes) -> void* {
        off = (off + 255) & ~(size_t)255;
        void* r = base + off;
        off += bytes;
        return r;
    };
    int*    t_node_bits = (int*)   take((size_t)Nn * 4);
    int*    counts      = (int*)   take((size_t)Nn * 4);
    int*    startb      = (int*)   take((size_t)Nn * 4);
    int*    cursor2     = (int*)   take((size_t)Nn * 4);
    int*    cursor      = (int*)   take(256);
    float*  t_safe      = (float*) take((size_t)Nn * 4);
    float*  decay       = (float*) take((size_t)Nn * LDIM * 4);
    int*    sorted_tgt  = (int*)   take((size_t)Bev * 4);
    float4* sorted_w    = (float4*)take((size_t)Bev * 16);
    _Float16* WpH = (_Float16*)take((size_t)NXY * KXY * 2);
    _Float16* WpL = (_Float16*)take((size_t)NXY * KXY * 2);
    _Float16* W2H = (_Float16*)take((size_t)MDIM * HDIM * 2);
    _Float16* W2L = (_Float16*)take((size_t)MDIM * HDIM * 2);
    _Float16* WeH = (_Float16*)take((size_t)MDIM * LM * 2);
    _Float16* WeL = (_Float16*)take((size_t)MDIM * LM * 2);
    _Float16* WsH = (_Float16*)take((size_t)EDIM * MDIM * 2);
    _Float16* WsL = (_Float16*)take((size_t)EDIM * MDIM * 2);
    _Float16* A1  = (_Float16*)take((size_t)Nn * KXY * 2);            // 15.4 MB
    _Float16* C1  = (_Float16*)take((size_t)Nn * NXY * 2);            // 25.6 MB
    _Float16* hbuf= (_Float16*)take((size_t)Nn * LDIM * HDIM * 2);    // 51.2 MB
    _Float16* updh= (_Float16*)take((size_t)Nn * LM * 2);             // 10.2 MB
    _Float16* ebuf= (_Float16*)take((size_t)Nn * MDIM * 2);           // 2.6 MB

    const int tb = 256;
    k_init<<<(Nn + tb - 1) / tb, tb, 0, stream>>>(t_node_bits, counts, cursor2, cursor, Nn);
    k_ev1<<<(Bev + tb - 1) / tb, tb, 0, stream>>>(src, timestamps, t_node_bits, counts, Bev);
    k_node<<<(Nn + tb - 1) / tb, tb, 0, stream>>>(t_node_bits, counts, last_update, lambs,
                                                  t_safe, decay, startb, cursor, Nn);
    k_ev2<<<(Bev + tb - 1) / tb, tb, 0, stream>>>(src, tgt, timestamps, t_safe,
                                                  startb, cursor2, lambs,
                                                  sorted_tgt, sorted_w, Bev);
    const int preptot = NXY * KXY + MDIM * HDIM + MDIM * LM + EDIM * MDIM;
    k_prep<<<(preptot + tb - 1) / tb, tb, 0, stream>>>(W1, W2, We, Ws,
                                                       WpH, WpL, W2H, W2L,
                                                       WeH, WeL, WsH, WsL);
    const int packtot = Nn * KXY;
    k_half<<<(packtot + tb - 1) / tb, tb, 0, stream>>>(memory, node_features, A1, packtot);

    const int mb1 = (Nn + 127) / 128;   // 157

    // G1: C1[20000][640](f16) = A1 @ Wpack   (K=384)
    k_mgemm<128, 0><<<dim3(mb1, NXY / 128), 256, 0, stream>>>(
        A1, WpH, WpL, C1, nullptr, Nn, NXY, KXY,
        nullptr, nullptr, nullptr, nullptr, nullptr);

    // gather: h f16 [80000][320]
    k_gather<<<5000, 256, 0, stream>>>(C1, sorted_w, sorted_tgt, startb, counts,
                                       W1, b1, hbuf, Nn);

    // G2: updated f16 = (h @ W2^T + b2) masked + memory*decay   (M=80000, N=64, K=320)
    k_mgemm<64, 1><<<dim3(Nn * LDIM / 128, 1), 256, 0, stream>>>(
        hbuf, W2H, W2L, updh, nullptr, Nn * LDIM, MDIM, HDIM,
        b2, memory, decay, counts, nullptr);

    // G3a: e f16 = leaky(updated @ We^T + be)   (M=20000, N=64, K=256)
    k_mgemm<64, 2><<<dim3(mb1, 1), 256, 0, stream>>>(
        updh, WeH, WeL, ebuf, nullptr, Nn, MDIM, LM,
        be, nullptr, nullptr, nullptr, nullptr);

    // G3b: out = theta*static + (1-theta)*leaky(e @ Ws^T + bs)   (M=20000, N=128, K=64)
    k_mgemm<128, 3><<<dim3(mb1, 1), 256, 0, stream>>>(
        ebuf, WsH, WsL, nullptr, out, Nn, EDIM, MDIM,
        bs, static_emb, nullptr, nullptr, theta);
}

// Round 10
// 276.167 us; speedup vs baseline: 1.6547x; 1.0840x over previous
//
#include <hip/hip_runtime.h>

// ---------------- problem constants ----------------
constexpr int LDIM = 4;
constexpr int MDIM = 64;
constexpr int FDIM = 128;
constexpr int EDIM = 128;
constexpr int RAWD = 641;
constexpr int HDIM = 320;
constexpr int LM   = LDIM * MDIM;   // 256
constexpr int KXY  = LM + FDIM;     // 384
constexpr int NXY  = 2 * HDIM;      // 640

typedef _Float16 f16x8 __attribute__((ext_vector_type(8)));
typedef _Float16 f16x4 __attribute__((ext_vector_type(4)));
typedef float    f32x4 __attribute__((ext_vector_type(4)));

constexpr float WSCALE  = 256.f;       // weights pre-scaled so lo-plane is f16-normal
constexpr float WSINV   = 1.f / 256.f; // exact pow2, applied in epilogue

// ---------------- small event/node kernels ----------------
__global__ void k_init(int* t_node_bits, int* counts, int* cursor2, int* cursor, int Nn)
{
    int n = blockIdx.x * blockDim.x + threadIdx.x;
    if (n < Nn) {
        t_node_bits[n] = 0xBF800000;  // -1.0f; timestamps >= 0
        counts[n]  = 0;
        cursor2[n] = 0;
    }
    if (n == 0) cursor[0] = 0;
}

__global__ void k_ev1(const int* __restrict__ src, const float* __restrict__ ts,
                      int* t_node_bits, int* counts, int Bev)
{
    int b = blockIdx.x * blockDim.x + threadIdx.x;
    if (b >= Bev) return;
    int s = src[b];
    atomicMax(&t_node_bits[s], __float_as_int(ts[b]));
    atomicAdd(&counts[s], 1);
}

__global__ void k_node(const int* __restrict__ t_node_bits, const int* __restrict__ counts,
                       const float* __restrict__ last_update, const float* __restrict__ lambs,
                       float* t_safe, float* decay, int* start, int* cursor, int Nn)
{
    int n = blockIdx.x * blockDim.x + threadIdx.x;
    if (n >= Nn) return;
    int c = counts[n];
    float lu = last_update[n];
    float tsn = (c > 0) ? __int_as_float(t_node_bits[n]) : lu;
    t_safe[n] = tsn;
    float d = tsn - lu;
    #pragma unroll
    for (int li = 0; li < LDIM; ++li)
        decay[n * LDIM + li] = expf(-d * lambs[li]);
    start[n] = atomicAdd(cursor, c);
}

__global__ void k_ev2(const int* __restrict__ src, const int* __restrict__ tgt,
                      const float* __restrict__ ts, const float* __restrict__ t_safe,
                      const int* __restrict__ start, int* cursor2,
                      const float* __restrict__ lambs,
                      int* sorted_tgt, float4* sorted_w, int Bev)
{
    int b = blockIdx.x * blockDim.x + threadIdx.x;
    if (b >= Bev) return;
    int s = src[b];
    int pos = start[s] + atomicAdd(&cursor2[s], 1);
    sorted_tgt[pos] = tgt[b];
    float dt = t_safe[s] - ts[b];
    sorted_w[pos] = make_float4(expf(-dt * lambs[0]), expf(-dt * lambs[1]),
                                expf(-dt * lambs[2]), expf(-dt * lambs[3]));
}

// ---------------- prep: weights [N][K] scaled f16 hi/lo + A1 f16 pack ----------------
__global__ void k_prep(const float* __restrict__ W1, const float* __restrict__ W2,
                       const float* __restrict__ We, const float* __restrict__ Ws,
                       const float* __restrict__ mem, const float* __restrict__ nf,
                       _Float16* WpH, _Float16* WpL, _Float16* W2H, _Float16* W2L,
                       _Float16* WeH, _Float16* WeL, _Float16* WsH, _Float16* WsL,
                       _Float16* A1, int packtot)
{
    int idx = blockIdx.x * blockDim.x + threadIdx.x;
    constexpr int T1 = NXY * KXY;    // 245760  Wpack [640][384]
    constexpr int T2 = MDIM * HDIM;  // 20480   W2 [64][320]
    constexpr int T3 = MDIM * LM;    // 16384   We [64][256]
    constexpr int T4 = EDIM * MDIM;  // 8192    Ws [128][64]
    constexpr int TW = T1 + T2 + T3 + T4;
    if (idx < TW) {
        float v; _Float16 *H, *L; int o;
        if (idx < T1) {
            int n = idx / KXY, k = idx % KXY;
            if (n < HDIM) {
                v = (k < LM) ? W1[(long)n * RAWD + k] : 0.f;            // X cols: src-mem
            } else {
                int hh = n - HDIM;
                v = (k < LM) ? W1[(long)hh * RAWD + LM + k]              // Y cols: tgt-mem
                             : W1[(long)hh * RAWD + 2 * LM + (k - LM)];  //         tgt-feat
            }
            H = WpH; L = WpL; o = idx;
        } else if (idx < T1 + T2) {
            o = idx - T1; v = W2[o]; H = W2H; L = W2L;
        } else if (idx < T1 + T2 + T3) {
            o = idx - T1 - T2; v = We[o]; H = WeH; L = WeL;
        } else {
            o = idx - T1 - T2 - T3; v = Ws[o]; H = WsH; L = WsL;
        }
        float xs = WSCALE * v;
        _Float16 hh = (_Float16)xs;
        _Float16 ll = (_Float16)(xs - (float)hh);
        H[o] = hh; L[o] = ll;
    } else {
        int r = idx - TW;
        if (r < packtot) {
            int n = r / KXY, k = r % KXY;
            float v = (k < LM) ? mem[(long)n * LM + k] : nf[(long)n * FDIM + (k - LM)];
            A1[r] = (_Float16)v;
        }
    }
}

// ---------------- gather: wave-per-node, vectorized f16 ----------------
// lane owns hidden indices [4*lane .. 4*lane+3] and [256+lane]
__global__ __launch_bounds__(256) void k_gather(
    const _Float16* __restrict__ C1, const float4* __restrict__ sorted_w,
    const int* __restrict__ sorted_tgt, const int* __restrict__ startb,
    const int* __restrict__ counts,
    const float* __restrict__ W1, const float* __restrict__ b1,
    _Float16* __restrict__ h, int Nn)
{
    const int lane = threadIdx.x & 63;
    const int wv   = threadIdx.x >> 6;          // wave id 0..3, one node per wave
    float4 b4 = *(const float4*)&b1[lane * 4];
    float bbA[4] = {b4.x, b4.y, b4.z, b4.w};
    float bbB = b1[256 + lane];
    float wlA[4], wlB;
    #pragma unroll
    for (int j = 0; j < 4; ++j)
        wlA[j] = W1[(long)(lane * 4 + j) * RAWD + (RAWD - 1)];
    wlB = W1[(long)(256 + lane) * RAWD + (RAWD - 1)];

    for (int n = blockIdx.x * 4 + wv; n < Nn; n += gridDim.x * 4) {
        int cnt = counts[n];
        if (cnt == 0) continue;                  // row poison masked in G2 epilogue
        int st = startb[n];
        float zA[4][4], zB[4], sw[4];
        #pragma unroll
        for (int li = 0; li < 4; ++li) { zB[li] = 0.f; sw[li] = 0.f; }
        #pragma unroll
        for (int j = 0; j < 4; ++j)
            #pragma unroll
            for (int li = 0; li < 4; ++li) zA[j][li] = 0.f;

        for (int e = 0; e < cnt; ++e) {
            float4 w = sorted_w[st + e];
            int    t = sorted_tgt[st + e];
            const _Float16* yr = C1 + (long)t * NXY + HDIM;
            f16x4 yA = *(const f16x4*)(yr + lane * 4);
            float  yB = (float)yr[256 + lane];
            float wf[4] = {w.x, w.y, w.z, w.w};
            sw[0] += w.x; sw[1] += w.y; sw[2] += w.z; sw[3] += w.w;
            #pragma unroll
            for (int j = 0; j < 4; ++j) {
                float yv = (float)yA[j];
                #pragma unroll
                for (int li = 0; li < 4; ++li) zA[j][li] += wf[li] * yv;
            }
            #pragma unroll
            for (int li = 0; li < 4; ++li) zB[li] += wf[li] * yB;
        }

        const _Float16* xr = C1 + (long)n * NXY;
        f16x4 xA4 = *(const f16x4*)(xr + lane * 4);
        float xB = (float)xr[256 + lane] + wlB;
        float xA[4];
        #pragma unroll
        for (int j = 0; j < 4; ++j) xA[j] = (float)xA4[j] + wlA[j];
        #pragma unroll
        for (int li = 0; li < 4; ++li) {
            _Float16* hr = h + ((long)n * LDIM + li) * HDIM;
            f16x4 hv;
            #pragma unroll
            for (int j = 0; j < 4; ++j)
                hv[j] = (_Float16)fmaxf(xA[j] * sw[li] + zA[j][li] + bbA[j], 0.f);
            *(f16x4*)(hr + lane * 4) = hv;
            hr[256 + lane] = (_Float16)fmaxf(xB * sw[li] + zB[li] + bbB, 0.f);
        }
    }
}

// ---------------- f16 2-product MFMA GEMM ----------------
// C[M][N] = A[M][K](f16) @ (Bh+Bl)[K][N], B stored [N][K] scaled by 256.
// LDS [rows][32k] f16 (64B rows), 16B-chunk XOR swizzle: phys_chunk = kc ^ ((row>>1)&3)
// (bank-base period is 2 rows at 64B stride -> (row>>1) spreads 4 chunk slots).
// 4 waves arranged WM x WN; wave tile (BM/WM) x (BN/WN).
// EPI: 0 -> f16 C; 1 -> updated f16 (A1-mem*decay + mask); 2 -> leaky f16; 3 -> f32 blend out.
template <int BM, int BN, int WM, int WN, int EPI>
__global__ __launch_bounds__(256) void k_mgemm(
    const _Float16* __restrict__ Ag,
    const _Float16* __restrict__ Bgh, const _Float16* __restrict__ Bgl,
    _Float16* __restrict__ Ch, float* __restrict__ Cf,
    int M, int N, int K,
    const float* __restrict__ bias, const _Float16* __restrict__ x1h,
    const float* __restrict__ x1f, const float* __restrict__ x2,
    const int* __restrict__ icnts, const float* __restrict__ theta)
{
    constexpr int BK = 32;
    constexpr int WROWS = BM / WM, WCOLS = BN / WN;
    constexpr int SM = WROWS / 16, SN = WCOLS / 16;
    static_assert(WM * WN == 4 && SM * 16 == WROWS && SN * 16 == WCOLS, "");
    static_assert((BM * 4) % 256 == 0 && (BN * 4) % 256 == 0, "");
    __shared__ _Float16 Ash[BM * BK];
    __shared__ _Float16 Bsh[BN * BK], Bsl[BN * BK];
    const int tid  = threadIdx.x;
    const int w    = tid >> 6, lane = tid & 63;
    const int wm   = w / WN,   wn   = w % WN;
    const int lrow = lane & 15, lq = lane >> 4;
    const long m0 = (long)blockIdx.x * BM;
    const int  n0 = blockIdx.y * BN;

    f32x4 acc[SM][SN];
    #pragma unroll
    for (int s = 0; s < SM; ++s)
        #pragma unroll
        for (int t = 0; t < SN; ++t) acc[s][t] = (f32x4){0.f, 0.f, 0.f, 0.f};

    for (int k0 = 0; k0 < K; k0 += BK) {
        // ---- stage A: BM rows x 4 16B-chunks ----
        #pragma unroll
        for (int f0 = 0; f0 < BM * 4; f0 += 256) {
            int c = f0 + tid;
            int row = c >> 2, kc = c & 3;
            long gm = m0 + row; if (gm > M - 1) gm = M - 1;
            int soff = row * BK + ((kc ^ ((row >> 1) & 3)) << 3);
            *(int4*)&Ash[soff] = *(const int4*)(Ag + gm * (long)K + k0 + kc * 8);
        }
        // ---- stage B: BN rows x 4 chunks, both planes ----
        #pragma unroll
        for (int f0 = 0; f0 < BN * 4; f0 += 256) {
            int c = f0 + tid;
            int row = c >> 2, kc = c & 3;
            long goff = (long)(n0 + row) * K + k0 + kc * 8;
            int soff = row * BK + ((kc ^ ((row >> 1) & 3)) << 3);
            *(int4*)&Bsh[soff] = *(const int4*)(Bgh + goff);
            *(int4*)&Bsl[soff] = *(const int4*)(Bgl + goff);
        }
        __syncthreads();

        f16x8 a[SM], bh[SN], bl[SN];
        #pragma unroll
        for (int s = 0; s < SM; ++s) {
            int row = wm * WROWS + s * 16 + lrow;
            a[s] = *(const f16x8*)&Ash[row * BK + ((lq ^ ((row >> 1) & 3)) << 3)];
        }
        #pragma unroll
        for (int t = 0; t < SN; ++t) {
            int row = wn * WCOLS + t * 16 + lrow;
            int off = row * BK + ((lq ^ ((row >> 1) & 3)) << 3);
            bh[t] = *(const f16x8*)&Bsh[off];
            bl[t] = *(const f16x8*)&Bsl[off];
        }
        #pragma unroll
        for (int s = 0; s < SM; ++s)
            #pragma unroll
            for (int t = 0; t < SN; ++t) {
                acc[s][t] = __builtin_amdgcn_mfma_f32_16x16x32_f16(a[s], bh[t], acc[s][t], 0, 0, 0);
                acc[s][t] = __builtin_amdgcn_mfma_f32_16x16x32_f16(a[s], bl[t], acc[s][t], 0, 0, 0);
            }
        __syncthreads();
    }

    // ---- epilogue (undo the 256x weight scale here) ----
    float th = 0.f;
    if constexpr (EPI == 3) th = theta[0];
    #pragma unroll
    for (int s = 0; s < SM; ++s) {
        #pragma unroll
        for (int t = 0; t < SN; ++t) {
            #pragma unroll
            for (int r = 0; r < 4; ++r) {
                long grow = m0 + wm * WROWS + s * 16 + lq * 4 + r;
                if (grow >= M) continue;
                int col = n0 + wn * WCOLS + t * 16 + lrow;
                float v = acc[s][t][r] * WSINV;
                long idx = grow * (long)N + col;
                if constexpr (EPI == 0) {
                    Ch[idx] = (_Float16)v;
                } else if constexpr (EPI == 1) {
                    // updated = memory(f16 A1)*decay + where(has, msg, 0)
                    float vb = v + bias[col];
                    bool has = icnts[grow >> 2] > 0;
                    float mv = (float)x1h[(grow >> 2) * KXY + (grow & 3) * MDIM + col];
                    float u = mv * x2[grow] + (has ? vb : 0.f);
                    Ch[idx] = (_Float16)u;
                } else if constexpr (EPI == 2) {
                    float u = v + bias[col];
                    u = u > 0.f ? u : 0.01f * u;
                    Ch[idx] = (_Float16)u;
                } else {
                    float u = v + bias[col];
                    u = u > 0.f ? u : 0.01f * u;
                    Cf[idx] = th * x1f[idx] + (1.f - th) * u;
                }
            }
        }
    }
}

// ---------------- launcher ----------------
extern "C" void kernel_launch(void* const* d_in, const int* in_sizes, int n_in,
                              void* d_out, int out_size, void* d_ws, size_t ws_size,
                              hipStream_t stream)
{
    (void)n_in; (void)out_size; (void)ws_size;
    const float* node_features = (const float*)d_in[0];
    const float* memory        = (const float*)d_in[1];
    const float* last_update   = (const float*)d_in[2];
    const float* lambs         = (const float*)d_in[3];
    const float* theta         = (const float*)d_in[4];
    const float* static_emb    = (const float*)d_in[5];
    const float* W1            = (const float*)d_in[6];
    const float* b1            = (const float*)d_in[7];
    const float* W2            = (const float*)d_in[8];
    const float* b2            = (const float*)d_in[9];
    const float* We            = (const float*)d_in[10];
    const float* be            = (const float*)d_in[11];
    const float* Ws            = (const float*)d_in[12];
    const float* bs            = (const float*)d_in[13];
    const float* timestamps    = (const float*)d_in[14];
    const int*   src           = (const int*)d_in[15];
    const int*   tgt           = (const int*)d_in[16];
    float* out = (float*)d_out;

    const int Nn  = in_sizes[2];   // 20000
    const int Bev = in_sizes[14];  // 100000

    char* base = (char*)d_ws;
    size_t off = 0;
    auto take = [&](size_t bytes) -> void* {
        off = (off + 255) & ~(size_t)255;
        void* r = base + off;
        off += bytes;
        return r;
    };
    int*    t_node_bits = (int*)   take((size_t)Nn * 4);
    int*    counts      = (int*)   take((size_t)Nn * 4);
    int*    startb      = (int*)   take((size_t)Nn * 4);
    int*    cursor2     = (int*)   take((size_t)Nn * 4);
    int*    cursor      = (int*)   take(256);
    float*  t_safe      = (float*) take((size_t)Nn * 4);
    float*  decay       = (float*) take((size_t)Nn * LDIM * 4);
    int*    sorted_tgt  = (int*)   take((size_t)Bev * 4);
    float4* sorted_w    = (float4*)take((size_t)Bev * 16);
    _Float16* WpH = (_Float16*)take((size_t)NXY * KXY * 2);
    _Float16* WpL = (_Float16*)take((size_t)NXY * KXY * 2);
    _Float16* W2H = (_Float16*)take((size_t)MDIM * HDIM * 2);
    _Float16* W2L = (_Float16*)take((size_t)MDIM * HDIM * 2);
    _Float16* WeH = (_Float16*)take((size_t)MDIM * LM * 2);
    _Float16* WeL = (_Float16*)take((size_t)MDIM * LM * 2);
    _Float16* WsH = (_Float16*)take((size_t)EDIM * MDIM * 2);
    _Float16* WsL = (_Float16*)take((size_t)EDIM * MDIM * 2);
    _Float16* A1  = (_Float16*)take((size_t)Nn * KXY * 2);            // 15.4 MB
    _Float16* C1  = (_Float16*)take((size_t)Nn * NXY * 2);            // 25.6 MB
    _Float16* hbuf= (_Float16*)take((size_t)Nn * LDIM * HDIM * 2);    // 51.2 MB
    _Float16* updh= (_Float16*)take((size_t)Nn * LM * 2);             // 10.2 MB
    _Float16* ebuf= (_Float16*)take((size_t)Nn * MDIM * 2);           // 2.6 MB

    const int tb = 256;
    k_init<<<(Nn + tb - 1) / tb, tb, 0, stream>>>(t_node_bits, counts, cursor2, cursor, Nn);
    k_ev1<<<(Bev + tb - 1) / tb, tb, 0, stream>>>(src, timestamps, t_node_bits, counts, Bev);
    k_node<<<(Nn + tb - 1) / tb, tb, 0, stream>>>(t_node_bits, counts, last_update, lambs,
                                                  t_safe, decay, startb, cursor, Nn);
    k_ev2<<<(Bev + tb - 1) / tb, tb, 0, stream>>>(src, tgt, timestamps, t_safe,
                                                  startb, cursor2, lambs,
                                                  sorted_tgt, sorted_w, Bev);
    const int packtot = Nn * KXY;
    const int preptot = NXY * KXY + MDIM * HDIM + MDIM * LM + EDIM * MDIM + packtot;
    k_prep<<<(preptot + tb - 1) / tb, tb, 0, stream>>>(W1, W2, We, Ws,
                                                       memory, node_features,
                                                       WpH, WpL, W2H, W2L,
                                                       WeH, WeL, WsH, WsL,
                                                       A1, packtot);

    const int mb64 = (Nn + 63) / 64;    // 313

    // G1: C1[20000][640](f16) = A1 @ Wpack   (K=384)  grid 313x5 = 1565 blocks
    k_mgemm<64, 128, 1, 4, 0><<<dim3(mb64, NXY / 128), 256, 0, stream>>>(
        A1, WpH, WpL, C1, nullptr, Nn, NXY, KXY,
        nullptr, nullptr, nullptr, nullptr, nullptr, nullptr);

    // gather: h f16 [80000][320]
    k_gather<<<5000, 256, 0, stream>>>(C1, sorted_w, sorted_tgt, startb, counts,
                                       W1, b1, hbuf, Nn);

    // G2: updated f16 = (h @ W2^T + b2) masked + mem*decay  (M=80000,N=64,K=320) 1250 blocks
    k_mgemm<64, 64, 2, 2, 1><<<dim3(Nn * LDIM / 64, 1), 256, 0, stream>>>(
        hbuf, W2H, W2L, updh, nullptr, Nn * LDIM, MDIM, HDIM,
        b2, A1, nullptr, decay, counts, nullptr);

    // G3a: e f16 = leaky(updated @ We^T + be)   (M=20000, N=64, K=256)  313 blocks
    k_mgemm<64, 64, 2, 2, 2><<<dim3(mb64, 1), 256, 0, stream>>>(
        updh, WeH, WeL, ebuf, nullptr, Nn, MDIM, LM,
        be, nullptr, nullptr, nullptr, nullptr, nullptr);

    // G3b: out = theta*static + (1-theta)*leaky(e @ Ws^T + bs)  (M=20000,N=128,K=64) 313 blocks
    k_mgemm<64, 128, 1, 4, 3><<<dim3(mb64, 1), 256, 0, stream>>>(
        ebuf, WsH, WsL, nullptr, out, Nn, EDIM, MDIM,
        bs, nullptr, static_emb, nullptr, nullptr, theta);
}